// Round 4
// baseline (856.659 us; speedup 1.0000x reference)
//
#include <hip/hip_runtime.h>
#include <stdint.h>

// d_out (f32) layout: seed [64][3][256] @0, x3 [64][128][256] @49152,
// fps x [64][3][512] @2146304.  x3 region doubles as x1 staging.
#define X3_OFF 49152
#define FPS_OFF 2146304

// ws (f32) layout: T1 @0, T1s @8192, T3 @16384, T3s @24576 (each [128][64]),
// featT [512][64] @32768.  Total 65536 floats = 256 KB.

// ---------------------------------------------------------------------------
// k_prep: featT[c][b] = feat[b][c]
// ---------------------------------------------------------------------------
__global__ void k_prep(const float* __restrict__ feat, float* __restrict__ ws) {
    int g = blockIdx.x * 256 + threadIdx.x;   // 32768
    int c = g >> 6, b = g & 63;
    ws[32768 + c * 64 + b] = feat[b * 512 + c];
}

// ---------------------------------------------------------------------------
// k_tterms: T[o][b] = sum_c W[o][128+c] * feat[b][c] for the 4 concat weights
// ---------------------------------------------------------------------------
__global__ void k_tterms(const float* __restrict__ w1, const float* __restrict__ ws1,
                         const float* __restrict__ w3, const float* __restrict__ ws3,
                         float* __restrict__ ws) {
    int g = blockIdx.x * 256 + threadIdx.x;   // 32768
    int which = g >> 13;
    int o = (g >> 6) & 127;
    int b = g & 63;
    const float* W = (which == 0) ? w1 : (which == 1) ? ws1
                     : (which == 2) ? w3 : ws3;
    const float* ft = ws + 32768;
    float acc = 0.f;
    for (int c = 0; c < 512; ++c)
        acc = fmaf(W[o * 640 + 128 + c], ft[c * 64 + b], acc);
    ws[which * 8192 + o * 64 + b] = acc;
}

// ---------------------------------------------------------------------------
// k_deconv (R6-proven): x1[b][o][k] = sum_c feat[b][c]*ps_w[c][o][k] + ps_b[o]
// acc[16], y-blocks=4.  // acc[32] variant spilled (R7: no launch_bounds)
// ---------------------------------------------------------------------------
__global__ void k_deconv(const float* __restrict__ psw,
                         const float* __restrict__ psb,
                         const float* __restrict__ ws,
                         float* __restrict__ stage) {
    int n = blockIdx.x * 256 + threadIdx.x;   // 32768 = o*256+k
    int b0 = blockIdx.y * 16;
    const float* featT = ws + 32768;
    float acc[16];
    float bias = psb[n >> 8];
#pragma unroll
    for (int j = 0; j < 16; ++j) acc[j] = bias;
    for (int c = 0; c < 512; ++c) {
        float pw = psw[c * 32768 + n];
#pragma unroll
        for (int j = 0; j < 16; ++j)
            acc[j] = fmaf(pw, featT[c * 64 + b0 + j], acc[j]);
    }
#pragma unroll
    for (int j = 0; j < 16; ++j)
        stage[(b0 + j) * 32768 + n] = acc[j];
}

// ---------------------------------------------------------------------------
// gemm8: acc[r] += sum_i S[i][lane] * Wg[(o0+r)*ld + i]  (o0 wave-uniform)
// ---------------------------------------------------------------------------
__device__ __forceinline__ void gemm8(const float* __restrict__ Wg, int ld, int o0,
                                      const float* S, int K, float acc[8], int lane) {
#pragma unroll 4
    for (int i = 0; i < K; ++i) {
        float x = S[i * 64 + lane];
#pragma unroll
        for (int r = 0; r < 8; ++r)
            acc[r] = fmaf(x, Wg[(o0 + r) * ld + i], acc[r]);
    }
}

// ---------------------------------------------------------------------------
// k_fused: per (b, 64-wide k-tile): x1 -> m1 -> m2 -> m3 -> m4/seed.
// ---------------------------------------------------------------------------
struct FusedW {
    const float *m1_w1, *m1_b1, *m1_w2, *m1_b2, *m1_ws, *m1_bs;
    const float *m2_w1, *m2_b1, *m2_w2, *m2_b2, *m2_ws, *m2_bs;
    const float *m3_w1, *m3_b1, *m3_w2, *m3_b2, *m3_ws, *m3_bs;
    const float *m4_w1, *m4_b1, *m4_w2, *m4_b2;
};

__global__ void __launch_bounds__(512)
k_fused(FusedW P, const float* __restrict__ ws, float* __restrict__ fout) {
    int b  = blockIdx.x >> 2;
    int k0 = (blockIdx.x & 3) * 64;
    int lane = threadIdx.x & 63;
    int wave = __builtin_amdgcn_readfirstlane(threadIdx.x >> 6);

    const float* T1  = ws;
    const float* T1s = ws + 8192;
    const float* T3  = ws + 16384;
    const float* T3s = ws + 24576;
    float* stage = fout + X3_OFF + b * 32768;

    __shared__ float Xs[8192];
    __shared__ float Hs[8192];

#pragma unroll
    for (int s = 0; s < 16; ++s) {
        int e = threadIdx.x + s * 512;
        int o = e >> 6, kk = e & 63;
        Xs[e] = stage[o * 256 + k0 + kk];
    }
    __syncthreads();

    float yreg[2][8];

    // ================= m1 =================
#pragma unroll
    for (int half = 0; half < 2; ++half) {
        int o0 = wave * 16 + half * 8;
        float acc[8];
#pragma unroll
        for (int r = 0; r < 8; ++r) acc[r] = T1[(o0 + r) * 64 + b] + P.m1_b1[o0 + r];
        gemm8(P.m1_w1, 640, o0, Xs, 128, acc, lane);
#pragma unroll
        for (int r = 0; r < 8; ++r) Hs[(o0 + r) * 64 + lane] = fmaxf(acc[r], 0.f);
    }
    __syncthreads();
#pragma unroll
    for (int half = 0; half < 2; ++half) {
        int o0 = wave * 16 + half * 8;
        float acc[8];
#pragma unroll
        for (int r = 0; r < 8; ++r)
            acc[r] = T1s[(o0 + r) * 64 + b] + P.m1_b2[o0 + r] + P.m1_bs[o0 + r];
        gemm8(P.m1_w2, 128, o0, Hs, 128, acc, lane);
        gemm8(P.m1_ws, 640, o0, Xs, 128, acc, lane);
#pragma unroll
        for (int r = 0; r < 8; ++r) yreg[half][r] = acc[r];
    }
    __syncthreads();
#pragma unroll
    for (int half = 0; half < 2; ++half) {
        int o0 = wave * 16 + half * 8;
#pragma unroll
        for (int r = 0; r < 8; ++r) Xs[(o0 + r) * 64 + lane] = yreg[half][r];
    }
    __syncthreads();

    // ================= m2 =================
    {
        int o0 = wave * 8;
        float acc[8];
#pragma unroll
        for (int r = 0; r < 8; ++r) acc[r] = P.m2_b1[o0 + r];
        gemm8(P.m2_w1, 128, o0, Xs, 128, acc, lane);
#pragma unroll
        for (int r = 0; r < 8; ++r) Hs[(o0 + r) * 64 + lane] = fmaxf(acc[r], 0.f);
    }
    __syncthreads();
#pragma unroll
    for (int half = 0; half < 2; ++half) {
        int o0 = wave * 16 + half * 8;
        float acc[8];
#pragma unroll
        for (int r = 0; r < 8; ++r) acc[r] = P.m2_b2[o0 + r] + P.m2_bs[o0 + r];
        gemm8(P.m2_w2, 64, o0, Hs, 64, acc, lane);
        gemm8(P.m2_ws, 128, o0, Xs, 128, acc, lane);
#pragma unroll
        for (int r = 0; r < 8; ++r) yreg[half][r] = acc[r];
    }
    __syncthreads();
#pragma unroll
    for (int half = 0; half < 2; ++half) {
        int o0 = wave * 16 + half * 8;
#pragma unroll
        for (int r = 0; r < 8; ++r) Xs[(o0 + r) * 64 + lane] = yreg[half][r];
    }
    __syncthreads();

    // ================= m3 =================
#pragma unroll
    for (int half = 0; half < 2; ++half) {
        int o0 = wave * 16 + half * 8;
        float acc[8];
#pragma unroll
        for (int r = 0; r < 8; ++r) acc[r] = T3[(o0 + r) * 64 + b] + P.m3_b1[o0 + r];
        gemm8(P.m3_w1, 640, o0, Xs, 128, acc, lane);
#pragma unroll
        for (int r = 0; r < 8; ++r) Hs[(o0 + r) * 64 + lane] = fmaxf(acc[r], 0.f);
    }
    __syncthreads();
#pragma unroll
    for (int half = 0; half < 2; ++half) {
        int o0 = wave * 16 + half * 8;
        float acc[8];
#pragma unroll
        for (int r = 0; r < 8; ++r)
            acc[r] = T3s[(o0 + r) * 64 + b] + P.m3_b2[o0 + r] + P.m3_bs[o0 + r];
        gemm8(P.m3_w2, 128, o0, Hs, 128, acc, lane);
        gemm8(P.m3_ws, 640, o0, Xs, 128, acc, lane);
#pragma unroll
        for (int r = 0; r < 8; ++r) yreg[half][r] = acc[r];
    }
    __syncthreads();
#pragma unroll
    for (int half = 0; half < 2; ++half) {
        int o0 = wave * 16 + half * 8;
#pragma unroll
        for (int r = 0; r < 8; ++r) {
            Xs[(o0 + r) * 64 + lane] = yreg[half][r];
            stage[(o0 + r) * 256 + k0 + lane] = yreg[half][r];
        }
    }
    __syncthreads();

    // ================= m4 / seed =================
    {
        int o0 = wave * 8;
        float acc[8];
#pragma unroll
        for (int r = 0; r < 8; ++r) acc[r] = P.m4_b1[o0 + r];
        gemm8(P.m4_w1, 128, o0, Xs, 128, acc, lane);
#pragma unroll
        for (int r = 0; r < 8; ++r) Hs[(o0 + r) * 64 + lane] = fmaxf(acc[r], 0.f);
    }
    __syncthreads();
    if (wave < 3) {
        int d = wave;
        float s = P.m4_b2[d];
        for (int j = 0; j < 64; ++j)
            s = fmaf(Hs[j * 64 + lane], P.m4_w2[d * 64 + j], s);
        fout[b * 768 + d * 256 + k0 + lane] = s;
    }
}

// ---------------------------------------------------------------------------
// Single-phase u64 DPP wave-64 max (canonical GCN pattern: row_shr 1/2/4/8 +
// row_bcast15 (rows 1,3) + row_bcast31 (rows 2,3)); result in lane 63.
// Key = (distbits<<32)|(8191-gidx): u64 max == (max dist, then min gidx).
// Identity old=0 is valid: all real keys > 0 (gidx <= 4351 -> low word > 0).
// ---------------------------------------------------------------------------
__device__ __forceinline__ unsigned long long wave_umax64_l63(unsigned hi, unsigned lo) {
    unsigned long long cur = (((unsigned long long)hi) << 32) | (unsigned long long)lo;
#define UMAX64_STEP(CTRL, RM)                                                       \
    {                                                                               \
        unsigned th = (unsigned)__builtin_amdgcn_update_dpp(                        \
            0, (int)(unsigned)(cur >> 32), CTRL, RM, 0xf, false);                   \
        unsigned tl = (unsigned)__builtin_amdgcn_update_dpp(                        \
            0, (int)(unsigned)(cur & 0xffffffffull), CTRL, RM, 0xf, false);         \
        unsigned long long o = (((unsigned long long)th) << 32) |                   \
                               (unsigned long long)tl;                              \
        if (o > cur) cur = o;                                                       \
    }
    UMAX64_STEP(0x111, 0xf)   // row_shr:1
    UMAX64_STEP(0x112, 0xf)   // row_shr:2
    UMAX64_STEP(0x114, 0xf)   // row_shr:4
    UMAX64_STEP(0x118, 0xf)   // row_shr:8
    UMAX64_STEP(0x142, 0xa)   // row_bcast:15 -> rows 1,3
    UMAX64_STEP(0x143, 0xc)   // row_bcast:31 -> rows 2,3
#undef UMAX64_STEP
    return cur;
}

// ---------------------------------------------------------------------------
// k_fps (v7 = 256t + tournament tree + single-phase u64 DPP):
// R3 lesson: barrier-locked waves can't hide each other's serial-phase
// latency; the lever is shortening the serial phase itself.
//   (a) per-thread argmax over 17 candidates: depth-5 tournament tree
//       (index-ordered, tie->left) instead of a 17-step serial select chain;
//   (b) wave reduce: ONE 6-step u64 DPP max on the packed key
//       (distbits<<32)|(8191-gidx) instead of two dependent DPP phases with
//       a readlane broadcast between them; lane 63 writes the wave candidate.
// Cross-wave merge + tie semantics unchanged (same u64 key, proven exact).
// Dist arithmetic unchanged: __fmul_rn/__fadd_rn bit-exact vs reference.
// ---------------------------------------------------------------------------
__global__ void __launch_bounds__(256)
k_fps(const float* __restrict__ seed, const float* __restrict__ partial,
      float* __restrict__ outx) {
    int b = blockIdx.x;
    int tid = threadIdx.x;        // 0..255
    int lane = tid & 63;
    int wv = tid >> 6;            // 0..3

    __shared__ float pts[4352 * 3];          // [idx][3]
    __shared__ unsigned long long cand[2][4];
    __shared__ int fars[512];

    // stage seed [b][3][256] -> pts[idx<256]
    pts[tid * 3 + 0] = seed[b * 768 + tid];
    pts[tid * 3 + 1] = seed[b * 768 + 256 + tid];
    pts[tid * 3 + 2] = seed[b * 768 + 512 + tid];
    // stage partial [b][4096][3] -> pts[256..4351]  (linear 12288 dwords)
#pragma unroll
    for (int j = 0; j < 48; ++j) {
        int e = tid + j * 256;
        pts[768 + e] = partial[b * 12288 + e];
    }
    if (tid == 0) fars[0] = 0;
    __syncthreads();

    float px[17], py[17], pz[17], dist[17];
#pragma unroll
    for (int s = 0; s < 17; ++s) {
        int g = s * 256 + tid;
        px[s] = pts[g * 3 + 0];
        py[s] = pts[g * 3 + 1];
        pz[s] = pts[g * 3 + 2];
        dist[s] = 1e10f;
    }
    float cx = pts[0], cy = pts[1], cz = pts[2];

    for (int t = 0; t < 511; ++t) {
        // ---- parallel phase: min-dist update (no serial select chain) ----
#pragma unroll
        for (int s = 0; s < 17; ++s) {
            float dx = px[s] - cx, dy = py[s] - cy, dz = pz[s] - cz;
            float d = __fadd_rn(__fadd_rn(__fmul_rn(dx, dx), __fmul_rn(dy, dy)),
                                __fmul_rn(dz, dz));
            dist[s] = fminf(dist[s], d);
        }
        // ---- tournament tree over s=0..16 (ascending index, tie->left ==
        //      exact first-index argmax; dist>=0 so f32 '>' is total) ----
        float tv[8]; int ts[8];
#pragma unroll
        for (int k = 0; k < 8; ++k) {
            bool g = dist[2 * k + 1] > dist[2 * k];
            tv[k] = g ? dist[2 * k + 1] : dist[2 * k];
            ts[k] = g ? (2 * k + 1) : (2 * k);
        }
#pragma unroll
        for (int k = 0; k < 4; ++k) {
            bool g = tv[2 * k + 1] > tv[2 * k];
            tv[k] = g ? tv[2 * k + 1] : tv[2 * k];
            ts[k] = g ? ts[2 * k + 1] : ts[2 * k];
        }
#pragma unroll
        for (int k = 0; k < 2; ++k) {
            bool g = tv[2 * k + 1] > tv[2 * k];
            tv[k] = g ? tv[2 * k + 1] : tv[2 * k];
            ts[k] = g ? ts[2 * k + 1] : ts[2 * k];
        }
        {
            bool g = tv[1] > tv[0];
            tv[0] = g ? tv[1] : tv[0];
            ts[0] = g ? ts[1] : ts[0];
        }
        {   // tail s=16 (largest indices) merged last as right operand
            bool g = dist[16] > tv[0];
            tv[0] = g ? dist[16] : tv[0];
            ts[0] = g ? 16 : ts[0];
        }
        unsigned bg = (unsigned)(ts[0] * 256 + tid);
        unsigned kHi = __float_as_uint(tv[0]);      // dist>=0: u32 order == f32
        unsigned kLo = 8191u - bg;                  // min-gidx tiebreak

        // ---- single-phase wave reduce; lane 63 holds wave best ----
        unsigned long long wk = wave_umax64_l63(kHi, kLo);
        if (lane == 63) cand[t & 1][wv] = wk;
        __syncthreads();

        // ---- cross-wave merge (broadcast reads, u64 keys exact) ----
        unsigned long long U0 = cand[t & 1][0];
        unsigned long long U1 = cand[t & 1][1];
        unsigned long long U2 = cand[t & 1][2];
        unsigned long long U3 = cand[t & 1][3];
        if (U1 > U0) U0 = U1;
        if (U3 > U2) U2 = U3;
        if (U2 > U0) U0 = U2;
        int bi = 8191 - (int)(U0 & 8191ull);
        cx = pts[bi * 3 + 0]; cy = pts[bi * 3 + 1]; cz = pts[bi * 3 + 2];
        if (tid == 0) fars[t + 1] = bi;
    }
    __syncthreads();

    // gather outputs: x [b][3][512]
#pragma unroll
    for (int j = 0; j < 2; ++j) {
        int n = tid + j * 256;
        int idx = fars[n];
        int ob = b * 1536 + n;
        outx[ob]        = pts[idx * 3 + 0];
        outx[ob + 512]  = pts[idx * 3 + 1];
        outx[ob + 1024] = pts[idx * 3 + 2];
    }
}

// ---------------------------------------------------------------------------
extern "C" void kernel_launch(void* const* d_in, const int* in_sizes, int n_in,
                              void* d_out, int out_size, void* d_ws, size_t ws_size,
                              hipStream_t stream) {
    (void)in_sizes; (void)n_in; (void)out_size; (void)ws_size;
    const float* feat    = (const float*)d_in[0];
    const float* partial = (const float*)d_in[3];
    const float* psw     = (const float*)d_in[4];
    const float* psb     = (const float*)d_in[5];

    FusedW P;
    P.m1_w1 = (const float*)d_in[6];  P.m1_b1 = (const float*)d_in[7];
    P.m1_w2 = (const float*)d_in[8];  P.m1_b2 = (const float*)d_in[9];
    P.m1_ws = (const float*)d_in[10]; P.m1_bs = (const float*)d_in[11];
    P.m2_w1 = (const float*)d_in[12]; P.m2_b1 = (const float*)d_in[13];
    P.m2_w2 = (const float*)d_in[14]; P.m2_b2 = (const float*)d_in[15];
    P.m2_ws = (const float*)d_in[16]; P.m2_bs = (const float*)d_in[17];
    P.m3_w1 = (const float*)d_in[18]; P.m3_b1 = (const float*)d_in[19];
    P.m3_w2 = (const float*)d_in[20]; P.m3_b2 = (const float*)d_in[21];
    P.m3_ws = (const float*)d_in[22]; P.m3_bs = (const float*)d_in[23];
    P.m4_w1 = (const float*)d_in[24]; P.m4_b1 = (const float*)d_in[25];
    P.m4_w2 = (const float*)d_in[26]; P.m4_b2 = (const float*)d_in[27];

    float* W = (float*)d_ws;
    float* out = (float*)d_out;

    k_prep<<<dim3(128), dim3(256), 0, stream>>>(feat, W);
    k_tterms<<<dim3(128), dim3(256), 0, stream>>>(P.m1_w1, P.m1_ws, P.m3_w1, P.m3_ws, W);
    k_deconv<<<dim3(128, 4), dim3(256), 0, stream>>>(psw, psb, W, out + X3_OFF);
    k_fused<<<dim3(256), dim3(512), 0, stream>>>(P, W, out);
    k_fps<<<dim3(64), dim3(256), 0, stream>>>(out, partial, out + FPS_OFF);
}

// Round 5
// 767.982 us; speedup vs baseline: 1.1155x; 1.1155x over previous
//
#include <hip/hip_runtime.h>
#include <stdint.h>

// d_out (f32) layout: seed [64][3][256] @0, x3 [64][128][256] @49152,
// fps x [64][3][512] @2146304.  x3 region doubles as x1 staging.
#define X3_OFF 49152
#define FPS_OFF 2146304

// ws (f32) layout: T1 @0, T1s @8192, T3 @16384, T3s @24576 (each [128][64]),
// featT [512][64] @32768.  Total 65536 floats = 256 KB.

// ---------------------------------------------------------------------------
// k_prep: featT[c][b] = feat[b][c]
// ---------------------------------------------------------------------------
__global__ void k_prep(const float* __restrict__ feat, float* __restrict__ ws) {
    int g = blockIdx.x * 256 + threadIdx.x;   // 32768
    int c = g >> 6, b = g & 63;
    ws[32768 + c * 64 + b] = feat[b * 512 + c];
}

// ---------------------------------------------------------------------------
// k_tterms: T[o][b] = sum_c W[o][128+c] * feat[b][c] for the 4 concat weights
// ---------------------------------------------------------------------------
__global__ void k_tterms(const float* __restrict__ w1, const float* __restrict__ ws1,
                         const float* __restrict__ w3, const float* __restrict__ ws3,
                         float* __restrict__ ws) {
    int g = blockIdx.x * 256 + threadIdx.x;   // 32768
    int which = g >> 13;
    int o = (g >> 6) & 127;
    int b = g & 63;
    const float* W = (which == 0) ? w1 : (which == 1) ? ws1
                     : (which == 2) ? w3 : ws3;
    const float* ft = ws + 32768;
    float acc = 0.f;
    for (int c = 0; c < 512; ++c)
        acc = fmaf(W[o * 640 + 128 + c], ft[c * 64 + b], acc);
    ws[which * 8192 + o * 64 + b] = acc;
}

// ---------------------------------------------------------------------------
// k_deconv (R6-proven): x1[b][o][k] = sum_c feat[b][c]*ps_w[c][o][k] + ps_b[o]
// acc[16], y-blocks=4.  // acc[32] variant spilled (R7: no launch_bounds)
// ---------------------------------------------------------------------------
__global__ void k_deconv(const float* __restrict__ psw,
                         const float* __restrict__ psb,
                         const float* __restrict__ ws,
                         float* __restrict__ stage) {
    int n = blockIdx.x * 256 + threadIdx.x;   // 32768 = o*256+k
    int b0 = blockIdx.y * 16;
    const float* featT = ws + 32768;
    float acc[16];
    float bias = psb[n >> 8];
#pragma unroll
    for (int j = 0; j < 16; ++j) acc[j] = bias;
    for (int c = 0; c < 512; ++c) {
        float pw = psw[c * 32768 + n];
#pragma unroll
        for (int j = 0; j < 16; ++j)
            acc[j] = fmaf(pw, featT[c * 64 + b0 + j], acc[j]);
    }
#pragma unroll
    for (int j = 0; j < 16; ++j)
        stage[(b0 + j) * 32768 + n] = acc[j];
}

// ---------------------------------------------------------------------------
// gemm8: acc[r] += sum_i S[i][lane] * Wg[(o0+r)*ld + i]  (o0 wave-uniform)
// ---------------------------------------------------------------------------
__device__ __forceinline__ void gemm8(const float* __restrict__ Wg, int ld, int o0,
                                      const float* S, int K, float acc[8], int lane) {
#pragma unroll 4
    for (int i = 0; i < K; ++i) {
        float x = S[i * 64 + lane];
#pragma unroll
        for (int r = 0; r < 8; ++r)
            acc[r] = fmaf(x, Wg[(o0 + r) * ld + i], acc[r]);
    }
}

// ---------------------------------------------------------------------------
// k_fused: per (b, 64-wide k-tile): x1 -> m1 -> m2 -> m3 -> m4/seed.
// ---------------------------------------------------------------------------
struct FusedW {
    const float *m1_w1, *m1_b1, *m1_w2, *m1_b2, *m1_ws, *m1_bs;
    const float *m2_w1, *m2_b1, *m2_w2, *m2_b2, *m2_ws, *m2_bs;
    const float *m3_w1, *m3_b1, *m3_w2, *m3_b2, *m3_ws, *m3_bs;
    const float *m4_w1, *m4_b1, *m4_w2, *m4_b2;
};

__global__ void __launch_bounds__(512)
k_fused(FusedW P, const float* __restrict__ ws, float* __restrict__ fout) {
    int b  = blockIdx.x >> 2;
    int k0 = (blockIdx.x & 3) * 64;
    int lane = threadIdx.x & 63;
    int wave = __builtin_amdgcn_readfirstlane(threadIdx.x >> 6);

    const float* T1  = ws;
    const float* T1s = ws + 8192;
    const float* T3  = ws + 16384;
    const float* T3s = ws + 24576;
    float* stage = fout + X3_OFF + b * 32768;

    __shared__ float Xs[8192];
    __shared__ float Hs[8192];

#pragma unroll
    for (int s = 0; s < 16; ++s) {
        int e = threadIdx.x + s * 512;
        int o = e >> 6, kk = e & 63;
        Xs[e] = stage[o * 256 + k0 + kk];
    }
    __syncthreads();

    float yreg[2][8];

    // ================= m1 =================
#pragma unroll
    for (int half = 0; half < 2; ++half) {
        int o0 = wave * 16 + half * 8;
        float acc[8];
#pragma unroll
        for (int r = 0; r < 8; ++r) acc[r] = T1[(o0 + r) * 64 + b] + P.m1_b1[o0 + r];
        gemm8(P.m1_w1, 640, o0, Xs, 128, acc, lane);
#pragma unroll
        for (int r = 0; r < 8; ++r) Hs[(o0 + r) * 64 + lane] = fmaxf(acc[r], 0.f);
    }
    __syncthreads();
#pragma unroll
    for (int half = 0; half < 2; ++half) {
        int o0 = wave * 16 + half * 8;
        float acc[8];
#pragma unroll
        for (int r = 0; r < 8; ++r)
            acc[r] = T1s[(o0 + r) * 64 + b] + P.m1_b2[o0 + r] + P.m1_bs[o0 + r];
        gemm8(P.m1_w2, 128, o0, Hs, 128, acc, lane);
        gemm8(P.m1_ws, 640, o0, Xs, 128, acc, lane);
#pragma unroll
        for (int r = 0; r < 8; ++r) yreg[half][r] = acc[r];
    }
    __syncthreads();
#pragma unroll
    for (int half = 0; half < 2; ++half) {
        int o0 = wave * 16 + half * 8;
#pragma unroll
        for (int r = 0; r < 8; ++r) Xs[(o0 + r) * 64 + lane] = yreg[half][r];
    }
    __syncthreads();

    // ================= m2 =================
    {
        int o0 = wave * 8;
        float acc[8];
#pragma unroll
        for (int r = 0; r < 8; ++r) acc[r] = P.m2_b1[o0 + r];
        gemm8(P.m2_w1, 128, o0, Xs, 128, acc, lane);
#pragma unroll
        for (int r = 0; r < 8; ++r) Hs[(o0 + r) * 64 + lane] = fmaxf(acc[r], 0.f);
    }
    __syncthreads();
#pragma unroll
    for (int half = 0; half < 2; ++half) {
        int o0 = wave * 16 + half * 8;
        float acc[8];
#pragma unroll
        for (int r = 0; r < 8; ++r) acc[r] = P.m2_b2[o0 + r] + P.m2_bs[o0 + r];
        gemm8(P.m2_w2, 64, o0, Hs, 64, acc, lane);
        gemm8(P.m2_ws, 128, o0, Xs, 128, acc, lane);
#pragma unroll
        for (int r = 0; r < 8; ++r) yreg[half][r] = acc[r];
    }
    __syncthreads();
#pragma unroll
    for (int half = 0; half < 2; ++half) {
        int o0 = wave * 16 + half * 8;
#pragma unroll
        for (int r = 0; r < 8; ++r) Xs[(o0 + r) * 64 + lane] = yreg[half][r];
    }
    __syncthreads();

    // ================= m3 =================
#pragma unroll
    for (int half = 0; half < 2; ++half) {
        int o0 = wave * 16 + half * 8;
        float acc[8];
#pragma unroll
        for (int r = 0; r < 8; ++r) acc[r] = T3[(o0 + r) * 64 + b] + P.m3_b1[o0 + r];
        gemm8(P.m3_w1, 640, o0, Xs, 128, acc, lane);
#pragma unroll
        for (int r = 0; r < 8; ++r) Hs[(o0 + r) * 64 + lane] = fmaxf(acc[r], 0.f);
    }
    __syncthreads();
#pragma unroll
    for (int half = 0; half < 2; ++half) {
        int o0 = wave * 16 + half * 8;
        float acc[8];
#pragma unroll
        for (int r = 0; r < 8; ++r)
            acc[r] = T3s[(o0 + r) * 64 + b] + P.m3_b2[o0 + r] + P.m3_bs[o0 + r];
        gemm8(P.m3_w2, 128, o0, Hs, 128, acc, lane);
        gemm8(P.m3_ws, 640, o0, Xs, 128, acc, lane);
#pragma unroll
        for (int r = 0; r < 8; ++r) yreg[half][r] = acc[r];
    }
    __syncthreads();
#pragma unroll
    for (int half = 0; half < 2; ++half) {
        int o0 = wave * 16 + half * 8;
#pragma unroll
        for (int r = 0; r < 8; ++r) {
            Xs[(o0 + r) * 64 + lane] = yreg[half][r];
            stage[(o0 + r) * 256 + k0 + lane] = yreg[half][r];
        }
    }
    __syncthreads();

    // ================= m4 / seed =================
    {
        int o0 = wave * 8;
        float acc[8];
#pragma unroll
        for (int r = 0; r < 8; ++r) acc[r] = P.m4_b1[o0 + r];
        gemm8(P.m4_w1, 128, o0, Xs, 128, acc, lane);
#pragma unroll
        for (int r = 0; r < 8; ++r) Hs[(o0 + r) * 64 + lane] = fmaxf(acc[r], 0.f);
    }
    __syncthreads();
    if (wave < 3) {
        int d = wave;
        float s = P.m4_b2[d];
        for (int j = 0; j < 64; ++j)
            s = fmaf(Hs[j * 64 + lane], P.m4_w2[d * 64 + j], s);
        fout[b * 768 + d * 256 + k0 + lane] = s;
    }
}

// ---------------------------------------------------------------------------
// DPP wave-64 reductions (canonical GCN pattern: row_shr 1/2/4/8 +
// row_bcast15 (rows 1,3) + row_bcast31 (rows 2,3)); result in lane 63.
// Identity-old makes masked/invalid lanes no-ops.  (v4-proven originals:
// these fuse to v_max_u32_dpp / v_min_u32_dpp — 1 instr per step.)
// ---------------------------------------------------------------------------
__device__ __forceinline__ unsigned wave_max_u32_l63(unsigned v) {
    unsigned t;
    t = (unsigned)__builtin_amdgcn_update_dpp(0, (int)v, 0x111, 0xf, 0xf, false); v = t > v ? t : v;
    t = (unsigned)__builtin_amdgcn_update_dpp(0, (int)v, 0x112, 0xf, 0xf, false); v = t > v ? t : v;
    t = (unsigned)__builtin_amdgcn_update_dpp(0, (int)v, 0x114, 0xf, 0xf, false); v = t > v ? t : v;
    t = (unsigned)__builtin_amdgcn_update_dpp(0, (int)v, 0x118, 0xf, 0xf, false); v = t > v ? t : v;
    t = (unsigned)__builtin_amdgcn_update_dpp(0, (int)v, 0x142, 0xa, 0xf, false); v = t > v ? t : v;
    t = (unsigned)__builtin_amdgcn_update_dpp(0, (int)v, 0x143, 0xc, 0xf, false); v = t > v ? t : v;
    return v;
}
__device__ __forceinline__ unsigned wave_min_u32_l63(unsigned v) {
    unsigned t;
    t = (unsigned)__builtin_amdgcn_update_dpp(-1, (int)v, 0x111, 0xf, 0xf, false); v = t < v ? t : v;
    t = (unsigned)__builtin_amdgcn_update_dpp(-1, (int)v, 0x112, 0xf, 0xf, false); v = t < v ? t : v;
    t = (unsigned)__builtin_amdgcn_update_dpp(-1, (int)v, 0x114, 0xf, 0xf, false); v = t < v ? t : v;
    t = (unsigned)__builtin_amdgcn_update_dpp(-1, (int)v, 0x118, 0xf, 0xf, false); v = t < v ? t : v;
    t = (unsigned)__builtin_amdgcn_update_dpp(-1, (int)v, 0x142, 0xa, 0xf, false); v = t < v ? t : v;
    t = (unsigned)__builtin_amdgcn_update_dpp(-1, (int)v, 0x143, 0xc, 0xf, false); v = t < v ? t : v;
    return v;
}

__device__ __forceinline__ unsigned umin_u(unsigned a, unsigned b) { return a < b ? a : b; }

// ---------------------------------------------------------------------------
// k_fps (v8 = v4 + tree select + candidate-xyz prefetch).
// R4 lesson: keep v4's issue structure (fused u32 DPP, serial-cheap ops);
// only shorten exposed serial latency without adding instructions:
//  (a) thread-local argmax: value-only fmaxf tree (depth ~4, lowers toward
//      v_max3_f32) + eq/min-u32 tree index recovery -> same instr count as
//      the 17-step serial chain but ~4x shallower dependency depth.
//      Exact: fmaxf returns an input bit-exactly; dist>=0, no NaN/-0;
//      min-s among (dist[s]==m) == first-index argmax tie semantics.
//  (b) each wave's lanes 0..2 prefetch pts[big] into candxyz BEFORE the
//      barrier (hidden in wave-arrival skew); post-barrier merge selects
//      xyz via cndmask -> removes the dependent bi->pts[bi*3] LDS
//      round-trip (~120 cyc) from the critical path.
// Dist arithmetic + DPP phases + key layout byte-identical to v4 (proven).
// ---------------------------------------------------------------------------
__global__ void __launch_bounds__(256)
k_fps(const float* __restrict__ seed, const float* __restrict__ partial,
      float* __restrict__ outx) {
    int b = blockIdx.x;
    int tid = threadIdx.x;        // 0..255
    int lane = tid & 63;
    int wv = tid >> 6;            // 0..3

    __shared__ float pts[4352 * 3];          // [idx][3]
    __shared__ unsigned long long cand[2][4];
    __shared__ float candxyz[2][4][3];
    __shared__ int fars[512];

    // stage seed [b][3][256] -> pts[idx<256]
    pts[tid * 3 + 0] = seed[b * 768 + tid];
    pts[tid * 3 + 1] = seed[b * 768 + 256 + tid];
    pts[tid * 3 + 2] = seed[b * 768 + 512 + tid];
    // stage partial [b][4096][3] -> pts[256..4351]  (linear 12288 dwords)
#pragma unroll
    for (int j = 0; j < 48; ++j) {
        int e = tid + j * 256;
        pts[768 + e] = partial[b * 12288 + e];
    }
    if (tid == 0) fars[0] = 0;
    __syncthreads();

    float px[17], py[17], pz[17], dist[17];
#pragma unroll
    for (int s = 0; s < 17; ++s) {
        int g = s * 256 + tid;
        px[s] = pts[g * 3 + 0];
        py[s] = pts[g * 3 + 1];
        pz[s] = pts[g * 3 + 2];
        dist[s] = 1e10f;
    }
    float cx = pts[0], cy = pts[1], cz = pts[2];

    for (int t = 0; t < 511; ++t) {
        // ---- parallel phase: min-dist update (bit-exact vs reference) ----
#pragma unroll
        for (int s = 0; s < 17; ++s) {
            float dx = px[s] - cx, dy = py[s] - cy, dz = pz[s] - cz;
            float d = __fadd_rn(__fadd_rn(__fmul_rn(dx, dx), __fmul_rn(dy, dy)),
                                __fmul_rn(dz, dz));
            dist[s] = fminf(dist[s], d);
        }
        // ---- thread-local max: shallow fmaxf tree (no index carried) ----
        float a0 = fmaxf(fmaxf(dist[0], dist[1]), dist[2]);
        float a1 = fmaxf(fmaxf(dist[3], dist[4]), dist[5]);
        float a2 = fmaxf(fmaxf(dist[6], dist[7]), dist[8]);
        float a3 = fmaxf(fmaxf(dist[9], dist[10]), dist[11]);
        float a4 = fmaxf(fmaxf(dist[12], dist[13]), dist[14]);
        float a5 = fmaxf(dist[15], dist[16]);
        float b0 = fmaxf(fmaxf(a0, a1), a2);
        float b1 = fmaxf(fmaxf(a3, a4), a5);
        float m  = fmaxf(b0, b1);
        // ---- index recovery: min s with dist[s]==m (parallel eq + tree) --
        unsigned e[17];
#pragma unroll
        for (int s = 0; s < 17; ++s)
            e[s] = (dist[s] == m) ? (unsigned)s : 63u;
        unsigned c0 = umin_u(umin_u(e[0], e[1]), e[2]);
        unsigned c1 = umin_u(umin_u(e[3], e[4]), e[5]);
        unsigned c2 = umin_u(umin_u(e[6], e[7]), e[8]);
        unsigned c3 = umin_u(umin_u(e[9], e[10]), e[11]);
        unsigned c4 = umin_u(umin_u(e[12], e[13]), e[14]);
        unsigned c5 = umin_u(e[15], e[16]);
        unsigned d0 = umin_u(umin_u(c0, c1), c2);
        unsigned d1 = umin_u(umin_u(c3, c4), c5);
        unsigned sm = umin_u(d0, d1);
        unsigned bg = (sm << 8) + (unsigned)tid;    // gidx = s*256 + tid

        // phase 1: wave max of dist bits (dist >= 0 so u32 order == f32 order)
        unsigned mv = wave_max_u32_l63(__float_as_uint(m));
        unsigned maxbits = (unsigned)__builtin_amdgcn_readlane((int)mv, 63);
        // phase 2: wave min of candidate global index among exact-max ties
        unsigned cg = (__float_as_uint(m) == maxbits) ? bg : 0xFFFFFFFFu;
        unsigned mgv = wave_min_u32_l63(cg);
        unsigned big = (unsigned)__builtin_amdgcn_readlane((int)mgv, 63);

        // wave candidate: key (v4 layout) + prefetched xyz (lanes 0..2)
        if (lane == 0)
            cand[t & 1][wv] = (((unsigned long long)maxbits) << 32) |
                              (unsigned long long)(8191u - big);
        if (lane < 3)
            candxyz[t & 1][wv][lane] = pts[big * 3 + lane];
        __syncthreads();

        // ---- cross-wave merge; xyz selected in registers (no pts read) ----
        unsigned long long U0 = cand[t & 1][0];
        unsigned long long U1 = cand[t & 1][1];
        unsigned long long U2 = cand[t & 1][2];
        unsigned long long U3 = cand[t & 1][3];
        float x0 = candxyz[t & 1][0][0], y0 = candxyz[t & 1][0][1], z0 = candxyz[t & 1][0][2];
        float x1 = candxyz[t & 1][1][0], y1 = candxyz[t & 1][1][1], z1 = candxyz[t & 1][1][2];
        float x2 = candxyz[t & 1][2][0], y2 = candxyz[t & 1][2][1], z2 = candxyz[t & 1][2][2];
        float x3 = candxyz[t & 1][3][0], y3 = candxyz[t & 1][3][1], z3 = candxyz[t & 1][3][2];
        bool s1 = U1 > U0;
        U0 = s1 ? U1 : U0; x0 = s1 ? x1 : x0; y0 = s1 ? y1 : y0; z0 = s1 ? z1 : z0;
        bool s3 = U3 > U2;
        U2 = s3 ? U3 : U2; x2 = s3 ? x3 : x2; y2 = s3 ? y3 : y2; z2 = s3 ? z3 : z2;
        bool s2 = U2 > U0;
        U0 = s2 ? U2 : U0; x0 = s2 ? x2 : x0; y0 = s2 ? y2 : y0; z0 = s2 ? z2 : z0;
        cx = x0; cy = y0; cz = z0;
        if (tid == 0) fars[t + 1] = 8191 - (int)(U0 & 8191ull);
    }
    __syncthreads();

    // gather outputs: x [b][3][512]
#pragma unroll
    for (int j = 0; j < 2; ++j) {
        int n = tid + j * 256;
        int idx = fars[n];
        int ob = b * 1536 + n;
        outx[ob]        = pts[idx * 3 + 0];
        outx[ob + 512]  = pts[idx * 3 + 1];
        outx[ob + 1024] = pts[idx * 3 + 2];
    }
}

// ---------------------------------------------------------------------------
extern "C" void kernel_launch(void* const* d_in, const int* in_sizes, int n_in,
                              void* d_out, int out_size, void* d_ws, size_t ws_size,
                              hipStream_t stream) {
    (void)in_sizes; (void)n_in; (void)out_size; (void)ws_size;
    const float* feat    = (const float*)d_in[0];
    const float* partial = (const float*)d_in[3];
    const float* psw     = (const float*)d_in[4];
    const float* psb     = (const float*)d_in[5];

    FusedW P;
    P.m1_w1 = (const float*)d_in[6];  P.m1_b1 = (const float*)d_in[7];
    P.m1_w2 = (const float*)d_in[8];  P.m1_b2 = (const float*)d_in[9];
    P.m1_ws = (const float*)d_in[10]; P.m1_bs = (const float*)d_in[11];
    P.m2_w1 = (const float*)d_in[12]; P.m2_b1 = (const float*)d_in[13];
    P.m2_w2 = (const float*)d_in[14]; P.m2_b2 = (const float*)d_in[15];
    P.m2_ws = (const float*)d_in[16]; P.m2_bs = (const float*)d_in[17];
    P.m3_w1 = (const float*)d_in[18]; P.m3_b1 = (const float*)d_in[19];
    P.m3_w2 = (const float*)d_in[20]; P.m3_b2 = (const float*)d_in[21];
    P.m3_ws = (const float*)d_in[22]; P.m3_bs = (const float*)d_in[23];
    P.m4_w1 = (const float*)d_in[24]; P.m4_b1 = (const float*)d_in[25];
    P.m4_w2 = (const float*)d_in[26]; P.m4_b2 = (const float*)d_in[27];

    float* W = (float*)d_ws;
    float* out = (float*)d_out;

    k_prep<<<dim3(128), dim3(256), 0, stream>>>(feat, W);
    k_tterms<<<dim3(128), dim3(256), 0, stream>>>(P.m1_w1, P.m1_ws, P.m3_w1, P.m3_ws, W);
    k_deconv<<<dim3(128, 4), dim3(256), 0, stream>>>(psw, psb, W, out + X3_OFF);
    k_fused<<<dim3(256), dim3(512), 0, stream>>>(P, W, out);
    k_fps<<<dim3(64), dim3(256), 0, stream>>>(out, partial, out + FPS_OFF);
}